// Round 2
// baseline (371.997 us; speedup 1.0000x reference)
//
#include <hip/hip_runtime.h>

typedef unsigned short u16;
typedef unsigned int u32;
typedef float f32x4 __attribute__((ext_vector_type(4)));
typedef __bf16 bf16x8 __attribute__((ext_vector_type(8)));

__device__ __forceinline__ u16 f2bf(float f) {
  u32 u = __float_as_uint(f);
  u += 0x7fffu + ((u >> 16) & 1u);
  return (u16)(u >> 16);
}
__device__ __forceinline__ float bf2f(u16 s) { return __uint_as_float(((u32)s) << 16); }
__device__ __forceinline__ float bf2f_lo(u32 w) { return __uint_as_float(w << 16); }
__device__ __forceinline__ float bf2f_hi(u32 w) { return __uint_as_float(w & 0xffff0000u); }

__device__ __forceinline__ void gload_lds16(const u16* g, u16* l) {
  __builtin_amdgcn_global_load_lds((const __attribute__((address_space(1))) void*)g,
                                   (__attribute__((address_space(3))) void*)l, 16, 0, 0);
}

// ---------------------------------------------------------------------------
// fp32 -> bf16 conversion for q,k,v (z selects source)
// ---------------------------------------------------------------------------
__global__ __launch_bounds__(256)
void convert3_f32_bf16(const float* __restrict__ a, const float* __restrict__ b,
                       const float* __restrict__ c, u16* __restrict__ dst0, long n) {
  const float* src = blockIdx.z == 0 ? a : (blockIdx.z == 1 ? b : c);
  u16* dst = dst0 + (long)blockIdx.z * n;
  long stride = (long)gridDim.x * blockDim.x * 4;
  for (long i = ((long)blockIdx.x * blockDim.x + threadIdx.x) * 4; i < n; i += stride) {
    float4 v = *(const float4*)(src + i);
    ushort4 o;
    o.x = f2bf(v.x); o.y = f2bf(v.y); o.z = f2bf(v.z); o.w = f2bf(v.w);
    *(ushort4*)(dst + i) = o;
  }
}

// ---------------------------------------------------------------------------
// weights fp32 [K=1024][N=1024] -> bf16 transposed [N][K]  (z selects matrix)
// ---------------------------------------------------------------------------
__global__ __launch_bounds__(256)
void wtrans(const float* __restrict__ w0, const float* __restrict__ w1,
            const float* __restrict__ w2, u16* __restrict__ out0) {
  const float* src = blockIdx.z == 0 ? w0 : (blockIdx.z == 1 ? w1 : w2);
  u16* dst = out0 + (long)blockIdx.z * 1048576;
  __shared__ float tile[64][65];
  int t = threadIdx.x;
  int r = t >> 4, c4 = (t & 15) * 4;
  int kb = blockIdx.y * 64;  // input row block (k = inp dim)
  int nb = blockIdx.x * 64;  // input col block (n = d_model)
#pragma unroll
  for (int rr = 0; rr < 64; rr += 16) {
    float4 v = *(const float4*)(src + (long)(kb + r + rr) * 1024 + nb + c4);
    tile[r + rr][c4 + 0] = v.x;
    tile[r + rr][c4 + 1] = v.y;
    tile[r + rr][c4 + 2] = v.z;
    tile[r + rr][c4 + 3] = v.w;
  }
  __syncthreads();
#pragma unroll
  for (int rr = 0; rr < 64; rr += 16) {
    ushort4 o;
    o.x = f2bf(tile[c4 + 0][r + rr]);
    o.y = f2bf(tile[c4 + 1][r + rr]);
    o.z = f2bf(tile[c4 + 2][r + rr]);
    o.w = f2bf(tile[c4 + 3][r + rr]);
    *(ushort4*)(dst + (long)(nb + r + rr) * 1024 + kb + c4) = o;
  }
}

// ---------------------------------------------------------------------------
// bf16 transpose: in [R][C] -> out [C][R], batched over z
// ---------------------------------------------------------------------------
__global__ __launch_bounds__(256)
void btrans(const u16* __restrict__ in0, u16* __restrict__ out0, int R, int C) {
  const u16* in = in0 + (long)blockIdx.z * R * C;
  u16* out = out0 + (long)blockIdx.z * R * C;
  __shared__ u16 tile[64][66];
  int t = threadIdx.x;
  int r = t >> 4, c4 = (t & 15) * 4;
  long rb = (long)blockIdx.y * 64;  // input row block
  long cb = (long)blockIdx.x * 64;  // input col block
#pragma unroll
  for (int rr = 0; rr < 64; rr += 16) {
    ushort4 v = *(const ushort4*)(in + (rb + r + rr) * C + cb + c4);
    tile[r + rr][c4 + 0] = v.x;
    tile[r + rr][c4 + 1] = v.y;
    tile[r + rr][c4 + 2] = v.z;
    tile[r + rr][c4 + 3] = v.w;
  }
  __syncthreads();
#pragma unroll
  for (int rr = 0; rr < 64; rr += 16) {
    ushort4 o;
    o.x = tile[c4 + 0][r + rr];
    o.y = tile[c4 + 1][r + rr];
    o.z = tile[c4 + 2][r + rr];
    o.w = tile[c4 + 3][r + rr];
    *(ushort4*)(out + (cb + r + rr) * R + rb + c4) = o;
  }
}

// ---------------------------------------------------------------------------
// GEMM: C[M][N] = A[M][K] * B^T  (B stored row-major [N][K]), bf16 in, epilogue
// 128x128 tile, BK=64, 256 threads = 4 waves (2x2), per-wave 64x64 = 4x4 frags
// ---------------------------------------------------------------------------
template <bool OUT_BF16, bool HAS_BIAS>
__global__ __launch_bounds__(256)
void gemm_bt(const u16* __restrict__ A, const u16* __restrict__ B,
             void* __restrict__ C, const float* __restrict__ bias,
             float scale, int M, int N, int K, long sA, long sB, long sC) {
  constexpr int BM = 128, BN = 128, BK = 64;
  __shared__ u16 As[BM * BK];
  __shared__ u16 Bs[BN * BK];
  const int tid = threadIdx.x;
  const int wid = tid >> 6, lane = tid & 63;
  const int wr = wid >> 1, wc = wid & 1;
  const int l15 = lane & 15, l4 = lane >> 4;
  const long z = blockIdx.z;
  const u16* Ab = A + z * sA;
  const u16* Bb = B + z * sB;
  const int bm = blockIdx.x * BM;
  const int bn = blockIdx.y * BN;

  f32x4 acc[4][4] = {};

  const u16* ga[4];
  const u16* gb[4];
  u16* la[4];
  u16* lb[4];
#pragma unroll
  for (int j = 0; j < 4; ++j) {
    int idx = j * 256 + tid;
    int row = idx >> 3, kc = idx & 7;
    ga[j] = Ab + (long)(bm + row) * K + kc * 8;
    gb[j] = Bb + (long)(bn + row) * K + kc * 8;
    la[j] = As + idx * 8;
    lb[j] = Bs + idx * 8;
  }

  for (int kt = 0; kt < K; kt += BK) {
    __syncthreads();
#pragma unroll
    for (int j = 0; j < 4; ++j) {
      gload_lds16(ga[j] + kt, la[j]);
      gload_lds16(gb[j] + kt, lb[j]);
    }
    __syncthreads();
#pragma unroll
    for (int kk = 0; kk < BK; kk += 32) {
      bf16x8 af[4], bfr[4];
#pragma unroll
      for (int i = 0; i < 4; ++i) {
        af[i] = *(const bf16x8*)(As + (wr * 64 + i * 16 + l15) * BK + kk + l4 * 8);
        bfr[i] = *(const bf16x8*)(Bs + (wc * 64 + i * 16 + l15) * BK + kk + l4 * 8);
      }
#pragma unroll
      for (int i = 0; i < 4; ++i)
#pragma unroll
        for (int j = 0; j < 4; ++j)
          acc[i][j] = __builtin_amdgcn_mfma_f32_16x16x32_bf16(af[i], bfr[j], acc[i][j], 0, 0, 0);
    }
  }

  // epilogue: D layout col=lane&15, row=(lane>>4)*4+r  [m89-verified]
#pragma unroll
  for (int j = 0; j < 4; ++j) {
    int col = bn + wc * 64 + j * 16 + l15;
    float bv = HAS_BIAS ? bias[col] : 0.f;
#pragma unroll
    for (int i = 0; i < 4; ++i) {
      int row0 = bm + wr * 64 + i * 16 + l4 * 4;
      f32x4 v = acc[i][j];
#pragma unroll
      for (int r = 0; r < 4; ++r) {
        float x = (v[r] + bv) * scale;
        long off = z * sC + (long)(row0 + r) * N + col;
        if (OUT_BF16)
          ((u16*)C)[off] = f2bf(x);
        else
          ((float*)C)[off] = x;
      }
    }
  }
}

// ---------------------------------------------------------------------------
// softmax over rows of S [4][2048][2048] bf16 (in-place), with additive mask
// one block (256 thr) per row; each thread owns 8 elements in registers
// ---------------------------------------------------------------------------
__device__ __forceinline__ float wave_max(float v) {
#pragma unroll
  for (int o = 32; o > 0; o >>= 1) v = fmaxf(v, __shfl_xor(v, o, 64));
  return v;
}
__device__ __forceinline__ float wave_sum(float v) {
#pragma unroll
  for (int o = 32; o > 0; o >>= 1) v += __shfl_xor(v, o, 64);
  return v;
}

__global__ __launch_bounds__(256)
void softmax_mask(u16* __restrict__ S, const float* __restrict__ mask) {
  long row = blockIdx.x;
  int q = (int)(row & 2047);
  u16* sp = S + row * 2048;
  const float* mp = mask + (long)q * 2048;
  int t = threadIdx.x;
  int wid = t >> 6;
  __shared__ float red[8];

  uint4 raw = *(const uint4*)(sp + t * 8);
  float4 m0 = *(const float4*)(mp + t * 8);
  float4 m1 = *(const float4*)(mp + t * 8 + 4);
  float x[8];
  x[0] = bf2f_lo(raw.x) + m0.x;
  x[1] = bf2f_hi(raw.x) + m0.y;
  x[2] = bf2f_lo(raw.y) + m0.z;
  x[3] = bf2f_hi(raw.y) + m0.w;
  x[4] = bf2f_lo(raw.z) + m1.x;
  x[5] = bf2f_hi(raw.z) + m1.y;
  x[6] = bf2f_lo(raw.w) + m1.z;
  x[7] = bf2f_hi(raw.w) + m1.w;

  float mx = x[0];
#pragma unroll
  for (int i = 1; i < 8; ++i) mx = fmaxf(mx, x[i]);
  mx = wave_max(mx);
  if ((t & 63) == 0) red[wid] = mx;
  __syncthreads();
  mx = fmaxf(fmaxf(red[0], red[1]), fmaxf(red[2], red[3]));

  float e[8], s = 0.f;
#pragma unroll
  for (int i = 0; i < 8; ++i) {
    e[i] = __expf(x[i] - mx);
    s += e[i];
  }
  s = wave_sum(s);
  if ((t & 63) == 0) red[4 + wid] = s;
  __syncthreads();
  s = (red[4] + red[5]) + (red[6] + red[7]);
  float inv = 1.f / s;

  uint4 outw;
  outw.x = (u32)f2bf(e[0] * inv) | ((u32)f2bf(e[1] * inv) << 16);
  outw.y = (u32)f2bf(e[2] * inv) | ((u32)f2bf(e[3] * inv) << 16);
  outw.z = (u32)f2bf(e[4] * inv) | ((u32)f2bf(e[5] * inv) << 16);
  outw.w = (u32)f2bf(e[6] * inv) | ((u32)f2bf(e[7] * inv) << 16);
  *(uint4*)(sp + t * 8) = outw;
}

// ---------------------------------------------------------------------------
// launch
// ---------------------------------------------------------------------------
extern "C" void kernel_launch(void* const* d_in, const int* in_sizes, int n_in,
                              void* d_out, int out_size, void* d_ws, size_t ws_size,
                              hipStream_t stream) {
  const float* q = (const float*)d_in[0];
  const float* k = (const float*)d_in[1];
  const float* v = (const float*)d_in[2];
  const float* mask = (const float*)d_in[3];
  const float* wq = (const float*)d_in[4];
  const float* bq = (const float*)d_in[5];
  const float* wk = (const float*)d_in[6];
  const float* bk = (const float*)d_in[7];
  const float* wv = (const float*)d_in[8];
  const float* bv = (const float*)d_in[9];
  float* out = (float*)d_out;

  // ws layout (ushort elems):
  //  [0 .. 25,165,824)   : qp, kp, vp           (3 x 8,388,608)
  //  [25,165,824 .. +3M) : wqT, wkT, wvT        (3 x 1,048,576)
  //  [28,311,552 .. end) : qb,kb,vb (phase 1) then S (16,777,216) + vpT (8,388,608)
  u16* ws = (u16*)d_ws;
  const long NP = 8388608;  // 8192*1024
  u16* qp = ws;
  u16* kp = ws + NP;
  u16* vp = ws + 2 * NP;
  u16* wT = ws + 3 * NP;          // 3 x 1048576
  u16* conv = ws + 3 * NP + 3145728;
  u16* qb = conv;
  u16* kb = conv + NP;
  u16* vb = conv + 2 * NP;
  u16* S = conv;                  // reuse (qb,kb dead after projections)
  u16* vpT = conv + 2 * NP;       // reuse (vb dead after projections)

  // 1. convert inputs to bf16
  convert3_f32_bf16<<<dim3(2048, 1, 3), 256, 0, stream>>>(q, k, v, conv, NP);
  // 2. convert + transpose weights
  wtrans<<<dim3(16, 16, 3), 256, 0, stream>>>(wq, wk, wv, wT);
  // 3. projections (Q gets the 1/sqrt(dk)=1/32 scale folded in)
  gemm_bt<true, true><<<dim3(64, 8, 1), 256, 0, stream>>>(
      qb, wT, (void*)qp, bq, 0.03125f, 8192, 1024, 1024, 0, 0, 0);
  gemm_bt<true, true><<<dim3(64, 8, 1), 256, 0, stream>>>(
      kb, wT + 1048576, (void*)kp, bk, 1.0f, 8192, 1024, 1024, 0, 0, 0);
  gemm_bt<true, true><<<dim3(64, 8, 1), 256, 0, stream>>>(
      vb, wT + 2097152, (void*)vp, bv, 1.0f, 8192, 1024, 1024, 0, 0, 0);
  // 4. transpose vp [b][2048][1024] -> vpT [b][1024][2048]
  btrans<<<dim3(16, 32, 4), 256, 0, stream>>>(vp, vpT, 2048, 1024);
  // 5. logits: S[b] = qp[b] @ kp[b]^T   (scale already folded into qp)
  gemm_bt<true, false><<<dim3(16, 16, 4), 256, 0, stream>>>(
      qp, kp, (void*)S, nullptr, 1.0f, 2048, 2048, 1024,
      (long)2048 * 1024, (long)2048 * 1024, (long)2048 * 2048);
  // 6. softmax with mask, in place on S
  softmax_mask<<<dim3(8192, 1, 1), 256, 0, stream>>>(S, mask);
  // 7. out[b] = P[b] @ vpT[b]^T  (fp32 out)
  gemm_bt<false, false><<<dim3(16, 8, 4), 256, 0, stream>>>(
      S, vpT, (void*)out, nullptr, 1.0f, 2048, 1024, 2048,
      (long)2048 * 2048, (long)1024 * 2048, (long)2048 * 1024);
}

// Round 3
// 353.972 us; speedup vs baseline: 1.0509x; 1.0509x over previous
//
#include <hip/hip_runtime.h>

typedef unsigned short u16;
typedef unsigned int u32;
typedef float f32x4 __attribute__((ext_vector_type(4)));
typedef __bf16 bf16x8 __attribute__((ext_vector_type(8)));

__device__ __forceinline__ u16 f2bf(float f) {
  u32 u = __float_as_uint(f);
  u += 0x7fffu + ((u >> 16) & 1u);
  return (u16)(u >> 16);
}
__device__ __forceinline__ float bf2f_lo(u32 w) { return __uint_as_float(w << 16); }
__device__ __forceinline__ float bf2f_hi(u32 w) { return __uint_as_float(w & 0xffff0000u); }

__device__ __forceinline__ void gload_lds16(const u16* g, u16* l) {
  __builtin_amdgcn_global_load_lds((const __attribute__((address_space(1))) void*)g,
                                   (__attribute__((address_space(3))) void*)l, 16, 0, 0);
}

// ---------------------------------------------------------------------------
// fp32 -> bf16 conversion for q,k,v (z selects source)
// ---------------------------------------------------------------------------
__global__ __launch_bounds__(256)
void convert3_f32_bf16(const float* __restrict__ a, const float* __restrict__ b,
                       const float* __restrict__ c, u16* __restrict__ dst0, long n) {
  const float* src = blockIdx.z == 0 ? a : (blockIdx.z == 1 ? b : c);
  u16* dst = dst0 + (long)blockIdx.z * n;
  long stride = (long)gridDim.x * blockDim.x * 4;
  for (long i = ((long)blockIdx.x * blockDim.x + threadIdx.x) * 4; i < n; i += stride) {
    float4 v = *(const float4*)(src + i);
    ushort4 o;
    o.x = f2bf(v.x); o.y = f2bf(v.y); o.z = f2bf(v.z); o.w = f2bf(v.w);
    *(ushort4*)(dst + i) = o;
  }
}

// ---------------------------------------------------------------------------
// weights fp32 [K=1024][N=1024] -> bf16 transposed [N][K]  (z selects matrix)
// ---------------------------------------------------------------------------
__global__ __launch_bounds__(256)
void wtrans(const float* __restrict__ w0, const float* __restrict__ w1,
            const float* __restrict__ w2, u16* __restrict__ out0) {
  const float* src = blockIdx.z == 0 ? w0 : (blockIdx.z == 1 ? w1 : w2);
  u16* dst = out0 + (long)blockIdx.z * 1048576;
  __shared__ float tile[64][65];
  int t = threadIdx.x;
  int r = t >> 4, c4 = (t & 15) * 4;
  int kb = blockIdx.y * 64;
  int nb = blockIdx.x * 64;
#pragma unroll
  for (int rr = 0; rr < 64; rr += 16) {
    float4 v = *(const float4*)(src + (long)(kb + r + rr) * 1024 + nb + c4);
    tile[r + rr][c4 + 0] = v.x;
    tile[r + rr][c4 + 1] = v.y;
    tile[r + rr][c4 + 2] = v.z;
    tile[r + rr][c4 + 3] = v.w;
  }
  __syncthreads();
#pragma unroll
  for (int rr = 0; rr < 64; rr += 16) {
    ushort4 o;
    o.x = f2bf(tile[c4 + 0][r + rr]);
    o.y = f2bf(tile[c4 + 1][r + rr]);
    o.z = f2bf(tile[c4 + 2][r + rr]);
    o.w = f2bf(tile[c4 + 3][r + rr]);
    *(ushort4*)(dst + (long)(nb + r + rr) * 1024 + kb + c4) = o;
  }
}

// ---------------------------------------------------------------------------
// 256x256 8-phase GEMM: C[M][N] = A[M][K] * B^T (B row-major [N][K]), bf16 in.
// 512 thr = 8 waves (2M x 4N); wave tile 128x64 = 8x4 frags of 16x16.
// BK=64; 2 K-tiles/iter; 8 phases/iter; counted vmcnt(6) at P4/P8 (T3+T4);
// T2 XOR swizzle (cblk ^= row&7) both-sides; T5 setprio around MFMA.
// MODE: 0 = bf16 out (logits), 1 = f32 out (PV),
//       2 = projections (bf16 + bias + z0-scale; z==2 writes C^T into Cct)
// ---------------------------------------------------------------------------
template <int MODE>
__global__ __launch_bounds__(512, 2)
void gemm8(const u16* __restrict__ A, const u16* __restrict__ B,
           void* __restrict__ Cn, u16* __restrict__ Cct,
           const float* __restrict__ bqp, const float* __restrict__ bkp,
           const float* __restrict__ bvp,
           int M, int N, int K, long sA, long sB, long sC) {
  __shared__ u16 lds[2][2][16384];  // [buf][A/B][256 rows x 64 k]
  const int tid = threadIdx.x;
  const int wid = tid >> 6, lane = tid & 63;
  const int wr = wid >> 2, wc = wid & 3;
  const int l15 = lane & 15, l4 = lane >> 4;
  const int z = blockIdx.z;
  const u16* Ab = A + (long)z * sA;
  const u16* Bb = B + (long)z * sB;
  const int bm = blockIdx.x * 256;
  const int bnn = blockIdx.y * 256;

  f32x4 acc[8][4] = {};
  bf16x8 af[4][2], pb0[2][2], pb1[2][2];

// stage A M-half region (rows {mh*64+[0,64)} u {128+mh*64+[0,64)}) of k-tile ks
// linear LDS dest, inverse-swizzled global src (rule #21 / m173)
#define STAGE_A(buf, mh, ks) {                                                \
    int d_ = ((mh) * 64 * 8) + tid;                                           \
    int r_ = d_ >> 3; int cs_ = (d_ & 7) ^ (r_ & 7);                          \
    gload_lds16(Ab + (long)(bm + r_) * K + (ks) + cs_ * 8,                    \
                &lds[buf][0][d_ * 8]);                                        \
    d_ += 1024; r_ = d_ >> 3; cs_ = (d_ & 7) ^ (r_ & 7);                      \
    gload_lds16(Ab + (long)(bm + r_) * K + (ks) + cs_ * 8,                    \
                &lds[buf][0][d_ * 8]);                                        \
  }

// stage B N-half region (4 stripes {s*64+nh*32+[0,32)}) of k-tile ks
#define STAGE_B(buf, nh, ks)                                                  \
  _Pragma("unroll") for (int qq_ = 0; qq_ < 2; ++qq_) {                       \
    int u_ = qq_ * 512 + tid;                                                 \
    int s_ = u_ >> 8, w_ = u_ & 255;                                          \
    int r_ = s_ * 64 + (nh) * 32 + (w_ >> 3);                                 \
    int cs_ = (w_ & 7) ^ (r_ & 7);                                            \
    gload_lds16(Bb + (long)(bnn + r_) * K + (ks) + cs_ * 8,                   \
                &lds[buf][1][(r_ * 8 + (w_ & 7)) * 8]);                       \
  }

#define LDA(buf, mh)                                                          \
  _Pragma("unroll") for (int i_ = 0; i_ < 4; ++i_)                            \
  _Pragma("unroll") for (int kk_ = 0; kk_ < 2; ++kk_) {                       \
    int r_ = wr * 128 + (mh) * 64 + i_ * 16 + l15;                            \
    int cb_ = (kk_ * 4 + l4) ^ (r_ & 7);                                      \
    af[i_][kk_] = *(const bf16x8*)&lds[buf][0][(r_ * 8 + cb_) * 8];           \
  }

#define LDB(buf, nh, dst)                                                     \
  _Pragma("unroll") for (int j_ = 0; j_ < 2; ++j_)                            \
  _Pragma("unroll") for (int kk_ = 0; kk_ < 2; ++kk_) {                       \
    int r_ = wc * 64 + (nh) * 32 + j_ * 16 + l15;                             \
    int cb_ = (kk_ * 4 + l4) ^ (r_ & 7);                                      \
    dst[j_][kk_] = *(const bf16x8*)&lds[buf][1][(r_ * 8 + cb_) * 8];          \
  }

#define MF(mh, nh, bfr)                                                       \
  _Pragma("unroll") for (int kk_ = 0; kk_ < 2; ++kk_)                         \
  _Pragma("unroll") for (int i_ = 0; i_ < 4; ++i_)                            \
  _Pragma("unroll") for (int j_ = 0; j_ < 2; ++j_)                            \
    acc[(mh) * 4 + i_][(nh) * 2 + j_] = __builtin_amdgcn_mfma_f32_16x16x32_bf16( \
        af[i_][kk_], bfr[j_][kk_], acc[(mh) * 4 + i_][(nh) * 2 + j_], 0, 0, 0);

#define BAR __builtin_amdgcn_s_barrier()
#define LGKM0 asm volatile("s_waitcnt lgkmcnt(0)" ::: "memory")
#define LGKM8 asm volatile("s_waitcnt lgkmcnt(8)" ::: "memory")
#define VM6 asm volatile("s_waitcnt vmcnt(6)" ::: "memory")
#define PRIO1 __builtin_amdgcn_s_setprio(1)
#define PRIO0 __builtin_amdgcn_s_setprio(0)

  // prologue: tile0 complete + tile1 {A[M0],B[N0],B[N1]}; tile1.A[M1] staged at P1
  STAGE_A(0, 0, 0); STAGE_B(0, 0, 0); STAGE_B(0, 1, 0); STAGE_A(0, 1, 0);
  STAGE_A(1, 0, 64); STAGE_B(1, 0, 64); STAGE_B(1, 1, 64);
  VM6;  // tile0 landed; tile1's 3 regions (6 loads) in flight
  BAR;

  for (int it = 0, nit = K >> 7; it < nit; ++it) {
    const int kt1 = it * 128 + 64;
    int ks0 = it * 128 + 128; if (ks0 >= K) ks0 -= K;
    int ks1 = kt1 + 128;      if (ks1 >= K) ks1 -= K;
    // P1: quadrant (M0,N0) of even tile
    LDA(0, 0); LDB(0, 0, pb0); STAGE_A(1, 1, kt1);
    LGKM8; BAR; LGKM0;
    PRIO1; MF(0, 0, pb0); PRIO0; BAR;
    // P2: (M0,N1)
    LDB(0, 1, pb1); STAGE_A(0, 0, ks0);
    BAR; LGKM0;
    PRIO1; MF(0, 1, pb1); PRIO0; BAR;
    // P3: (M1,N1)
    LDA(0, 1); STAGE_B(0, 0, ks0);
    BAR; LGKM0;
    PRIO1; MF(1, 1, pb1); PRIO0; BAR;
    // P4: (M1,N0)
    STAGE_B(0, 1, ks0); VM6;
    BAR;
    PRIO1; MF(1, 0, pb0); PRIO0; BAR;
    // P5: (M0,N0) of odd tile
    LDA(1, 0); LDB(1, 0, pb0); STAGE_A(0, 1, ks0);
    LGKM8; BAR; LGKM0;
    PRIO1; MF(0, 0, pb0); PRIO0; BAR;
    // P6: (M0,N1)
    LDB(1, 1, pb1); STAGE_A(1, 0, ks1);
    BAR; LGKM0;
    PRIO1; MF(0, 1, pb1); PRIO0; BAR;
    // P7: (M1,N1)
    LDA(1, 1); STAGE_B(1, 0, ks1);
    BAR; LGKM0;
    PRIO1; MF(1, 1, pb1); PRIO0; BAR;
    // P8: (M1,N0)
    STAGE_B(1, 1, ks1); VM6;
    BAR;
    PRIO1; MF(1, 0, pb0); PRIO0; BAR;
  }
  asm volatile("s_waitcnt vmcnt(0)" ::: "memory");

  // epilogue: C/D layout col=lane&15, row=(lane>>4)*4+r (m89-verified)
  const int crow0 = bm + wr * 128 + l4 * 4;
  const int ccol0 = bnn + wc * 64 + l15;
  if constexpr (MODE == 0) {
    u16* Cp = (u16*)Cn + (long)z * sC;
#pragma unroll
    for (int m = 0; m < 8; ++m)
#pragma unroll
      for (int n = 0; n < 4; ++n)
#pragma unroll
        for (int r = 0; r < 4; ++r)
          Cp[(long)(crow0 + m * 16 + r) * N + (ccol0 + n * 16)] = f2bf(acc[m][n][r]);
  } else if constexpr (MODE == 1) {
    float* Cp = (float*)Cn + (long)z * sC;
#pragma unroll
    for (int m = 0; m < 8; ++m)
#pragma unroll
      for (int n = 0; n < 4; ++n)
#pragma unroll
        for (int r = 0; r < 4; ++r)
          Cp[(long)(crow0 + m * 16 + r) * N + (ccol0 + n * 16)] = acc[m][n][r];
  } else {
    const float* bias = z == 0 ? bqp : (z == 1 ? bkp : bvp);
    const float sc = z == 0 ? 0.03125f : 1.0f;
    if (z < 2) {
      u16* Cp = (u16*)Cn + (long)z * sC;
#pragma unroll
      for (int n = 0; n < 4; ++n) {
        float bb = bias[ccol0 + n * 16];
#pragma unroll
        for (int m = 0; m < 8; ++m)
#pragma unroll
          for (int r = 0; r < 4; ++r)
            Cp[(long)(crow0 + m * 16 + r) * N + (ccol0 + n * 16)] =
                f2bf((acc[m][n][r] + bb) * sc);
      }
    } else {
      // V projection: write transposed vpT[batch][d][s], 4 consecutive s per lane
      const int batch = bm >> 11;
      u16* Cp = Cct + (long)batch * 2097152;
      const int sbase = (bm & 2047) + wr * 128 + l4 * 4;
#pragma unroll
      for (int n = 0; n < 4; ++n) {
        int d = ccol0 + n * 16;
        float bb = bias[d];
#pragma unroll
        for (int m = 0; m < 8; ++m) {
          ushort4 o;
          o.x = f2bf(acc[m][n][0] + bb);
          o.y = f2bf(acc[m][n][1] + bb);
          o.z = f2bf(acc[m][n][2] + bb);
          o.w = f2bf(acc[m][n][3] + bb);
          *(ushort4*)&Cp[(long)d * 2048 + sbase + m * 16] = o;
        }
      }
    }
  }
#undef STAGE_A
#undef STAGE_B
#undef LDA
#undef LDB
#undef MF
#undef BAR
#undef LGKM0
#undef LGKM8
#undef VM6
#undef PRIO1
#undef PRIO0
}

// ---------------------------------------------------------------------------
// softmax over rows of S [4][2048][2048] bf16 (in-place), with additive mask
// ---------------------------------------------------------------------------
__device__ __forceinline__ float wave_max(float v) {
#pragma unroll
  for (int o = 32; o > 0; o >>= 1) v = fmaxf(v, __shfl_xor(v, o, 64));
  return v;
}
__device__ __forceinline__ float wave_sum(float v) {
#pragma unroll
  for (int o = 32; o > 0; o >>= 1) v += __shfl_xor(v, o, 64);
  return v;
}

__global__ __launch_bounds__(256)
void softmax_mask(u16* __restrict__ S, const float* __restrict__ mask) {
  long row = blockIdx.x;
  int q = (int)(row & 2047);
  u16* sp = S + row * 2048;
  const float* mp = mask + (long)q * 2048;
  int t = threadIdx.x;
  int wid = t >> 6;
  __shared__ float red[8];

  uint4 raw = *(const uint4*)(sp + t * 8);
  float4 m0 = *(const float4*)(mp + t * 8);
  float4 m1 = *(const float4*)(mp + t * 8 + 4);
  float x[8];
  x[0] = bf2f_lo(raw.x) + m0.x;
  x[1] = bf2f_hi(raw.x) + m0.y;
  x[2] = bf2f_lo(raw.y) + m0.z;
  x[3] = bf2f_hi(raw.y) + m0.w;
  x[4] = bf2f_lo(raw.z) + m1.x;
  x[5] = bf2f_hi(raw.z) + m1.y;
  x[6] = bf2f_lo(raw.w) + m1.z;
  x[7] = bf2f_hi(raw.w) + m1.w;

  float mx = x[0];
#pragma unroll
  for (int i = 1; i < 8; ++i) mx = fmaxf(mx, x[i]);
  mx = wave_max(mx);
  if ((t & 63) == 0) red[wid] = mx;
  __syncthreads();
  mx = fmaxf(fmaxf(red[0], red[1]), fmaxf(red[2], red[3]));

  float e[8], s = 0.f;
#pragma unroll
  for (int i = 0; i < 8; ++i) {
    e[i] = __expf(x[i] - mx);
    s += e[i];
  }
  s = wave_sum(s);
  if ((t & 63) == 0) red[4 + wid] = s;
  __syncthreads();
  s = (red[4] + red[5]) + (red[6] + red[7]);
  float inv = 1.f / s;

  uint4 outw;
  outw.x = (u32)f2bf(e[0] * inv) | ((u32)f2bf(e[1] * inv) << 16);
  outw.y = (u32)f2bf(e[2] * inv) | ((u32)f2bf(e[3] * inv) << 16);
  outw.z = (u32)f2bf(e[4] * inv) | ((u32)f2bf(e[5] * inv) << 16);
  outw.w = (u32)f2bf(e[6] * inv) | ((u32)f2bf(e[7] * inv) << 16);
  *(uint4*)(sp + t * 8) = outw;
}

// ---------------------------------------------------------------------------
// launch
// ---------------------------------------------------------------------------
extern "C" void kernel_launch(void* const* d_in, const int* in_sizes, int n_in,
                              void* d_out, int out_size, void* d_ws, size_t ws_size,
                              hipStream_t stream) {
  const float* q = (const float*)d_in[0];
  const float* k = (const float*)d_in[1];
  const float* v = (const float*)d_in[2];
  const float* mask = (const float*)d_in[3];
  const float* wq = (const float*)d_in[4];
  const float* bq = (const float*)d_in[5];
  const float* wk = (const float*)d_in[6];
  const float* bk = (const float*)d_in[7];
  const float* wv = (const float*)d_in[8];
  const float* bv = (const float*)d_in[9];
  float* out = (float*)d_out;

  // ws layout (u16 elems):
  //  qp  [0, NP)            kp [NP, 2NP)        vpT [2NP, 3NP)
  //  wT  [3NP, 3NP+3M)      conv/qb,kb,vb [3NP+3M, +3NP)  (S reuses conv, 2NP)
  u16* ws = (u16*)d_ws;
  const long NP = 8388608;  // 8192*1024
  u16* qp = ws;
  u16* kp = ws + NP;
  u16* vpT = ws + 2 * NP;
  u16* wT = ws + 3 * NP;
  u16* conv = ws + 3 * NP + 3145728;
  u16* S = conv;

  // 1. inputs -> bf16
  convert3_f32_bf16<<<dim3(2048, 1, 3), 256, 0, stream>>>(q, k, v, conv, NP);
  // 2. weights -> bf16 transposed [N][K]
  wtrans<<<dim3(16, 16, 3), 256, 0, stream>>>(wq, wk, wv, wT);
  // 3. projections, z=3 batched (z0=Q with 1/32 scale, z1=K, z2=V writes vpT^T)
  gemm8<2><<<dim3(32, 4, 3), 512, 0, stream>>>(
      conv, wT, (void*)qp, vpT, bq, bk, bv, 8192, 1024, 1024, NP, 1048576, NP);
  // 4. logits: S[b] = qp[b] @ kp[b]^T (scale folded into qp)
  gemm8<0><<<dim3(8, 8, 4), 512, 0, stream>>>(
      qp, kp, (void*)S, nullptr, nullptr, nullptr, nullptr,
      2048, 2048, 1024, 2097152, 2097152, 4194304);
  // 5. softmax + mask, in place
  softmax_mask<<<dim3(8192, 1, 1), 256, 0, stream>>>(S, mask);
  // 6. out[b] = P[b] @ vpT[b]^T  (f32 out)
  gemm8<1><<<dim3(8, 4, 4), 512, 0, stream>>>(
      S, vpT, (void*)out, nullptr, nullptr, nullptr, nullptr,
      2048, 1024, 2048, 4194304, 2097152, 2097152);
}